// Round 1
// baseline (1748.365 us; speedup 1.0000x reference)
//
#include <hip/hip_runtime.h>
#include <hip/hip_bf16.h>
#include <math.h>

#define B_   4096
#define T_   16
#define F_   256
#define U_   512
#define M_   8
#define K_   768    // F+U
#define NRS  4096   // U*M
#define NC   8192   // combined R|S output cols
#define LNT  1.1512925f  // 0.5*ln(10)

typedef __bf16 bf16_t;
typedef bf16_t bf16x8 __attribute__((ext_vector_type(8)));
typedef bf16_t bf16x4 __attribute__((ext_vector_type(4)));
typedef float  f32x4  __attribute__((ext_vector_type(4)));

__device__ inline void gl_lds16(const void* g, void* lds) {
    __builtin_amdgcn_global_load_lds(
        (const __attribute__((address_space(1))) unsigned int*)g,
        (__attribute__((address_space(3))) unsigned int*)lds, 16, 0, 0);
}

#define VMCNT(n) asm volatile("s_waitcnt vmcnt(" #n ")" ::: "memory")
#define LGKM0()  asm volatile("s_waitcnt lgkmcnt(0)" ::: "memory")
#define BAR()    __builtin_amdgcn_s_barrier()

// ---------------------------------------------------------------------------
// Stage one 256x32 bf16 slot (16KB): 512 thr x 2 x 16B. LDS dest is LINEAR
// (global_load_lds requirement); the T2 swizzle is applied by inverse-
// permuting the per-lane GLOBAL source column (both-sides-or-neither rule).
// Swizzle: 16B-slot index s -> s ^ ((row>>1)&3). k0 is a multiple of 32 so a
// slot never straddles the xt|hprev K-boundary at 256.
// ---------------------------------------------------------------------------
__device__ inline void stageA(bf16_t* dst, const bf16_t* xt, const bf16_t* hp,
                              int m0, int k0, int tid) {
    const int r = tid >> 2;
    const int c = ((tid & 3) ^ ((tid >> 3) & 3)) * 8;
    const bf16_t *s0, *s1;
    if (k0 < F_) {
        s0 = xt + (size_t)(m0 + r) * F_ + k0 + c;
        s1 = xt + (size_t)(m0 + r + 128) * F_ + k0 + c;
    } else {
        s0 = hp + (size_t)(m0 + r) * U_ + (k0 - F_) + c;
        s1 = hp + (size_t)(m0 + r + 128) * U_ + (k0 - F_) + c;
    }
    gl_lds16(s0, (char*)dst + tid * 16);
    gl_lds16(s1, (char*)dst + (tid + 512) * 16);
}

__device__ inline void stageB(bf16_t* dst, const bf16_t* Bt, int n0, int k0, int tid) {
    const int r = tid >> 2;
    const int c = ((tid & 3) ^ ((tid >> 3) & 3)) * 8;
    gl_lds16(Bt + (size_t)(n0 + r) * K_ + k0 + c,       (char*)dst + tid * 16);
    gl_lds16(Bt + (size_t)(n0 + r + 128) * K_ + k0 + c, (char*)dst + (tid + 512) * 16);
}

__device__ inline void ds_read4(const bf16_t* base, bf16x8 (&v)[4]) {
    v[0] = *(const bf16x8*)(base);
    v[1] = *(const bf16x8*)(base + 512);
    v[2] = *(const bf16x8*)(base + 1024);
    v[3] = *(const bf16x8*)(base + 1536);
}

template <int H>
__device__ inline void mfma16(f32x4 (&acc)[8][4], const bf16x8 (&a)[4],
                              const bf16x8 (&b)[4]) {
    __builtin_amdgcn_s_setprio(1);
#pragma unroll
    for (int i = 0; i < 4; ++i)
#pragma unroll
        for (int j = 0; j < 4; ++j)
            acc[H * 4 + i][j] = __builtin_amdgcn_mfma_f32_16x16x32_bf16(
                a[i], b[j], acc[H * 4 + i][j], 0, 0, 0);
    __builtin_amdgcn_s_setprio(0);
}

// ---------------------------------------------------------------------------
// Combined R|S GEMM, 8-phase deep-pipelined 256x256 tile, fused softmax
// epilogue. 8 waves (2Mx4N), per-wave 128x64. LDS: per matrix 4 slots of
// 256x32 (K-half lo/hi x parity dbuf) = 128 KiB total. Raw s_barrier only
// (no __syncthreads -> no implicit vmcnt(0) drain); counted vmcnt(8) twice
// per K-tile keeps 4 slot-stages (8 loads) in flight across barriers.
// Per K-tile t (parity p), 4 phases:
//  ph1: read A-lo[p] Mh0 + B-lo[p];      stage A-hi(t+1)           ; MFMA h0
//  ph2: read A-lo[p] Mh1;                stage B-hi(t+1); vmcnt(8) ; MFMA h1
//  ph3: read A-hi[p] Mh0 + B-hi[p];      stage A-lo(t+2)           ; MFMA h0
//  ph4: read A-hi[p] Mh1;                stage B-lo(t+2); vmcnt(8) ; MFMA h1
// Every slot's restage is >=1 phase after its last read (end-barrier
// publishes all waves' read completion -> no overwrite race).
// ---------------------------------------------------------------------------
__global__ __launch_bounds__(512, 2) void gemm_rs_8ph(
    const bf16_t* __restrict__ xt,     // [B_][F_]
    const bf16_t* __restrict__ hprev,  // [B_][U_]
    const bf16_t* __restrict__ Bt,     // WrsT [NC][K_] (perm)
    const float*  __restrict__ biasP,  // [NC] (perm)
    const bf16_t* __restrict__ hhat,   // [B_][NRS]
    bf16_t* __restrict__ rh,           // [B_][U_]
    bf16_t* __restrict__ sbuf)         // [B_][NRS]
{
    __shared__ bf16_t Asl[2][2][256 * 32];   // [khalf][parity] 64 KiB
    __shared__ bf16_t Bsl[2][2][256 * 32];   // 64 KiB

    const int tid  = threadIdx.x;
    const int lane = tid & 63;
    const int wave = tid >> 6;

    // bijective XCD swizzle (512 blocks, 512%8==0): chunk n-fastest so the
    // 16 R-n-blocks sharing an hhat row-panel (2MB) stay on one XCD's L2.
    const int lin = blockIdx.y * 16 + blockIdx.x;
    const int swz = (lin & 7) * 64 + (lin >> 3);
    const int m0 = (swz >> 5) * 256;
    const int n0 = (swz & 31) * 256;

    const int wm = wave >> 2;          // 0..1
    const int wn = wave & 3;           // 0..3
    const int lr = lane & 15;
    const int kq = lane >> 4;
    // T2 read-side swizzle: 16B-slot = kq ^ ((row>>1)&3); row=16a+lr -> lane-uniform.
    const int cr = (kq ^ ((lr >> 1) & 3)) * 8;

    const int aoff0 = (wm * 128 + lr) * 32 + cr;        // M-half 0
    const int aoff1 = (wm * 128 + 64 + lr) * 32 + cr;   // M-half 1
    const int boff  = (wn * 64 + lr) * 32 + cr;

    f32x4 acc[8][4] = {};
    bf16x8 a[4], b[4];

    // Prologue: 6 slots in flight; vmcnt(8) -> A-lo(0),B-lo(0) landed.
    stageA(&Asl[0][0][0], xt, hprev, m0, 0,  tid);
    stageB(&Bsl[0][0][0], Bt, n0, 0,  tid);
    stageA(&Asl[1][0][0], xt, hprev, m0, 32, tid);
    stageB(&Bsl[1][0][0], Bt, n0, 32, tid);
    stageA(&Asl[0][1][0], xt, hprev, m0, 64, tid);
    stageB(&Bsl[0][1][0], Bt, n0, 64, tid);
    VMCNT(8);
    BAR();

#define TILE(T, VM2, VM4, S12, S34)                                           \
  {                                                                           \
    const int p_ = (T) & 1, pn_ = p_ ^ 1;                                     \
    /* phase 1 */                                                             \
    ds_read4(&Asl[0][p_][0] + aoff0, a);                                      \
    ds_read4(&Bsl[0][p_][0] + boff, b);                                       \
    if (S12) stageA(&Asl[1][pn_][0], xt, hprev, m0, ((T) + 1) * 64 + 32, tid);\
    BAR(); LGKM0();                                                           \
    mfma16<0>(acc, a, b);                                                     \
    BAR();                                                                    \
    /* phase 2 */                                                             \
    ds_read4(&Asl[0][p_][0] + aoff1, a);                                      \
    if (S12) stageB(&Bsl[1][pn_][0], Bt, n0, ((T) + 1) * 64 + 32, tid);       \
    VMCNT(VM2); BAR(); LGKM0();                                               \
    mfma16<1>(acc, a, b);                                                     \
    BAR();                                                                    \
    /* phase 3 */                                                             \
    ds_read4(&Asl[1][p_][0] + aoff0, a);                                      \
    ds_read4(&Bsl[1][p_][0] + boff, b);                                       \
    if (S34) stageA(&Asl[0][p_][0], xt, hprev, m0, ((T) + 2) * 64, tid);      \
    BAR(); LGKM0();                                                           \
    mfma16<0>(acc, a, b);                                                     \
    BAR();                                                                    \
    /* phase 4 */                                                             \
    ds_read4(&Asl[1][p_][0] + aoff1, a);                                      \
    if (S34) stageB(&Bsl[0][p_][0], Bt, n0, ((T) + 2) * 64, tid);             \
    VMCNT(VM4); BAR(); LGKM0();                                               \
    mfma16<1>(acc, a, b);                                                     \
    BAR();                                                                    \
  }

    for (int tt = 0; tt < 10; ++tt) TILE(tt, 8, 8, 1, 1);
    TILE(10, 8, 4, 1, 0);   // no t+2 stages; ph4 protects ph1(11): 2 slots after
    TILE(11, 0, 0, 0, 0);   // no stages left; drain before ph3(11) reads
#undef TILE

    // ------------------- fused softmax epilogue (unchanged math) -----------
    const int nb  = n0 + wn * 64;
    const int u3  = lane & 7;
    const int m0v = ((lane >> 3) & 1) * 4;
    const bool is_r = nb < NRS;

    float bj[4];
#pragma unroll
    for (int j = 0; j < 4; ++j) bj[j] = biasP[nb + j * 16 + lr];

#pragma unroll
    for (int mi = 0; mi < 8; ++mi) {
        const int rowb = m0 + wm * 128 + mi * 16 + kq * 4;
#pragma unroll
        for (int r = 0; r < 4; ++r) {
            const int row = rowb + r;
            float e[4], sum = 0.f;
#pragma unroll
            for (int j = 0; j < 4; ++j) {
                float v = acc[mi][j][r] + bj[j];
                float d = v - (float)(m0v + j) * LNT;
                e[j] = __expf(-d * d);
                sum += e[j];
            }
            sum += __shfl_xor(sum, 8, 64);
            const float inv = 1.0f / sum;
            if (is_r) {
                bf16x4 h4 = *(const bf16x4*)(hhat + (size_t)row * NRS + nb + u3 * 8 + m0v);
                float rhv = 0.f;
#pragma unroll
                for (int j = 0; j < 4; ++j) rhv += e[j] * inv * (float)h4[j];
                rhv += __shfl_xor(rhv, 8, 64);
                if ((lane & 8) == 0)
                    rh[(size_t)row * U_ + (nb >> 3) + u3] = (bf16_t)rhv;
            } else {
                bf16x4 pv;
#pragma unroll
                for (int j = 0; j < 4; ++j) pv[j] = (bf16_t)(e[j] * inv);
                *(bf16x4*)(sbuf + (size_t)row * NRS + (nb - NRS) + u3 * 8 + m0v) = pv;
            }
        }
    }
}

// ---------------------------------------------------------------------------
// q GEMM (64x64 tiles, grid 64x8=512) + fused state update; writes this
// step's hidden into hall slice t (persistent; next rs reads it as hprev).
// ---------------------------------------------------------------------------
__global__ __launch_bounds__(256) void gemm_q_up(
    const bf16_t* __restrict__ xt,     // [B_][F_]
    const bf16_t* __restrict__ rh,     // [B_][U_]
    const bf16_t* __restrict__ Bq,     // WqT [U_][K_]
    const float*  __restrict__ bq,
    const bf16_t* __restrict__ sbuf,
    bf16_t* __restrict__ hhat,
    bf16_t* __restrict__ hnext)        // hall slice t: [B_][U_]
{
    __shared__ bf16_t Al[2][64 * 32];
    __shared__ bf16_t Bl[2][64 * 32];

    const int tid  = threadIdx.x;
    const int lane = tid & 63;
    const int wave = tid >> 6;
    const int m0 = blockIdx.x * 64;
    const int n0 = blockIdx.y * 64;
    const int wm = (wave & 1) * 32;
    const int wn = (wave >> 1) * 32;
    const int lr = lane & 15;
    const int kq = lane >> 4;

    f32x4 acc[2][2] = {};

    const int rA = tid >> 2;
    const int kc = (tid & 3) * 8;

    for (int kk = 0; kk < K_; kk += 64) {
        const bf16_t* arow;
        int cbase;
        if (kk < F_) { arow = xt + (size_t)(m0 + rA) * F_; cbase = kk; }
        else         { arow = rh + (size_t)(m0 + rA) * U_; cbase = kk - F_; }

        __syncthreads();
        gl_lds16(arow + cbase + kc,      (char*)&Al[0][0] + tid * 16);
        gl_lds16(arow + cbase + 32 + kc, (char*)&Al[1][0] + tid * 16);
        gl_lds16(Bq + (size_t)(n0 + rA) * K_ + kk + kc,      (char*)&Bl[0][0] + tid * 16);
        gl_lds16(Bq + (size_t)(n0 + rA) * K_ + kk + 32 + kc, (char*)&Bl[1][0] + tid * 16);
        __syncthreads();

#pragma unroll
        for (int s = 0; s < 2; s++) {
            bf16x8 af[2], bfr[2];
#pragma unroll
            for (int i = 0; i < 2; i++)
                af[i] = *(const bf16x8*)(&Al[s][0] + (wm + i * 16 + lr) * 32 + kq * 8);
#pragma unroll
            for (int i = 0; i < 2; i++)
                bfr[i] = *(const bf16x8*)(&Bl[s][0] + (wn + i * 16 + lr) * 32 + kq * 8);
#pragma unroll
            for (int i = 0; i < 2; i++)
#pragma unroll
                for (int j = 0; j < 2; j++)
                    acc[i][j] = __builtin_amdgcn_mfma_f32_16x16x32_bf16(
                        af[i], bfr[j], acc[i][j], 0, 0, 0);
        }
    }

    const float DEC[8] = {0.0f, 0.9658531f, 0.9827783f, 0.9884856f,
                          0.9913518f, 0.9930754f, 0.9942261f, 0.9950489f};

#pragma unroll
    for (int i = 0; i < 2; i++) {
        const int rowb = m0 + wm + i * 16 + kq * 4;
#pragma unroll
        for (int j = 0; j < 2; j++) {
            const int u = n0 + wn + j * 16 + lr;
            const float bv = bq[u];
#pragma unroll
            for (int r = 0; r < 4; r++) {
                const int row = rowb + r;
                const float q = tanhf(acc[i][j][r] + bv);
                const size_t base = (size_t)row * NRS + u * 8;
                bf16x8 s8 = *(const bf16x8*)(sbuf + base);
                bf16x8 h8 = *(const bf16x8*)(hhat + base);
                bf16x8 ho;
                float hs = 0.f;
#pragma unroll
                for (int m = 0; m < 8; m++) {
                    float s = (float)s8[m];
                    float h = (float)h8[m];
                    float hn = ((1.f - s) * h + s * q) * DEC[m];
                    ho[m] = (bf16_t)hn;
                    hs += hn;
                }
                *(bf16x8*)(hhat + base) = ho;
                hnext[(size_t)row * U_ + u] = (bf16_t)hs;
            }
        }
    }
}

// dst[p][K_] = bf16(src[K_][NRS] col L), rows permuted within 64-groups.
__global__ void transpose_perm(const float* __restrict__ src, bf16_t* __restrict__ dst) {
    __shared__ float tl[32][33];
    int k0 = blockIdx.x * 32, n0 = blockIdx.y * 32;
    int tx = threadIdx.x & 31, ty = threadIdx.x >> 5;
#pragma unroll
    for (int i = 0; i < 32; i += 8)
        tl[ty + i][tx] = src[(size_t)(k0 + ty + i) * NRS + n0 + tx];
    __syncthreads();
#pragma unroll
    for (int i = 0; i < 32; i += 8) {
        int n = n0 + ty + i;
        int m = n & 7, u3v = (n >> 3) & 7;
        int p = (n & ~63) + (m & 3) * 16 + (m >> 2) * 8 + u3v;
        dst[(size_t)p * K_ + k0 + tx] = (bf16_t)tl[tx][ty + i];
    }
}

// plain transpose: dst[N][K_] = bf16(src[K_][N]^T)
__global__ void transpose_plain(const float* __restrict__ src, bf16_t* __restrict__ dst, int N) {
    __shared__ float tl[32][33];
    int k0 = blockIdx.x * 32, n0 = blockIdx.y * 32;
    int tx = threadIdx.x & 31, ty = threadIdx.x >> 5;
#pragma unroll
    for (int i = 0; i < 32; i += 8)
        tl[ty + i][tx] = src[(size_t)(k0 + ty + i) * N + n0 + tx];
    __syncthreads();
#pragma unroll
    for (int i = 0; i < 32; i += 8)
        dst[(size_t)(n0 + ty + i) * K_ + k0 + tx] = (bf16_t)tl[tx][ty + i];
}

__global__ void bias_perm(const float* __restrict__ b_r, const float* __restrict__ b_s,
                          float* __restrict__ biasP) {
    int p = blockIdx.x * 256 + threadIdx.x;  // NC
    int pr = p & 63, j = pr >> 4, lr = pr & 15;
    int L = (p & ~63) + (lr & 7) * 8 + ((lr >> 3) & 1) * 4 + j;
    biasP[p] = (L < NRS) ? b_r[L] : b_s[L - NRS];
}

// xall[t][b][f] = bf16(x[b][t][f])
__global__ void xall_build(const float* __restrict__ x, bf16_t* __restrict__ xall) {
    int idx = blockIdx.x * 256 + threadIdx.x;  // B_*T_*F_
    int b = idx >> 12;
    int rem = idx & 4095;
    int t = rem >> 8, f = rem & 255;
    xall[((size_t)t * B_ + b) * F_ + f] = (bf16_t)x[idx];
}

// One launch for all T steps: out[b,t,:] = hall[t][b][:] @ Wout + bout.
__global__ __launch_bounds__(256) void out_all(
    const bf16_t* __restrict__ hall,   // [T_][B_][U_] (slices 1..16 of alloc)
    const float* __restrict__ Wout,
    const float* __restrict__ bout,
    float* __restrict__ out)
{
    int row = blockIdx.x * 4 + (threadIdx.x >> 6);  // t*B_ + b
    int lane = threadIdx.x & 63;
    bf16x8 h8 = *(const bf16x8*)(hall + (size_t)row * U_ + lane * 8);
    float p0 = 0, p1 = 0, p2 = 0;
#pragma unroll
    for (int k = 0; k < 8; k++) {
        float h = (float)h8[k];
        int u = lane * 8 + k;
        p0 += h * Wout[u * 3 + 0];
        p1 += h * Wout[u * 3 + 1];
        p2 += h * Wout[u * 3 + 2];
    }
    for (int off = 32; off; off >>= 1) {
        p0 += __shfl_down(p0, off, 64);
        p1 += __shfl_down(p1, off, 64);
        p2 += __shfl_down(p2, off, 64);
    }
    if (lane == 0) {
        int t = row >> 12, b = row & (B_ - 1);
        size_t o = ((size_t)b * T_ + t) * 3;
        out[o + 0] = p0 + bout[0];
        out[o + 1] = p1 + bout[1];
        out[o + 2] = p2 + bout[2];
    }
}

extern "C" void kernel_launch(void* const* d_in, const int* in_sizes, int n_in,
                              void* d_out, int out_size, void* d_ws, size_t ws_size,
                              hipStream_t stream) {
    const float* x   = (const float*)d_in[0];
    const float* W_r = (const float*)d_in[1];
    const float* b_r = (const float*)d_in[2];
    const float* W_q = (const float*)d_in[3];
    const float* b_q = (const float*)d_in[4];
    const float* W_s = (const float*)d_in[5];
    const float* b_s = (const float*)d_in[6];
    const float* W_o = (const float*)d_in[7];
    const float* b_o = (const float*)d_in[8];
    float* out = (float*)d_out;

    char* ws = (char*)d_ws;
    bf16_t* hhat  = (bf16_t*)ws; ws += (size_t)B_ * NRS * 2;         // 32 MB
    bf16_t* sbuf  = (bf16_t*)ws; ws += (size_t)B_ * NRS * 2;         // 32 MB
    bf16_t* xall  = (bf16_t*)ws; ws += (size_t)B_ * T_ * F_ * 2;     // 32 MB
    bf16_t* hall  = (bf16_t*)ws; ws += (size_t)(T_ + 1) * B_ * U_ * 2; // 68 MB
    bf16_t* rh    = (bf16_t*)ws; ws += (size_t)B_ * U_ * 2;          // 4 MB
    bf16_t* WrsT  = (bf16_t*)ws; ws += (size_t)NC * K_ * 2;          // 12 MB
    bf16_t* WqT   = (bf16_t*)ws; ws += (size_t)U_ * K_ * 2;          // 0.75 MB
    float*  biasP = (float*)ws;  ws += (size_t)NC * 4;               // 32 KB

    hipMemsetAsync(hhat, 0, (size_t)B_ * NRS * 2, stream);
    hipMemsetAsync(hall, 0, (size_t)B_ * U_ * 2, stream);  // slice 0 = h(-1)=0
    xall_build<<<B_ * T_ * F_ / 256, 256, 0, stream>>>(x, xall);
    transpose_perm<<<dim3(K_ / 32, NRS / 32), 256, 0, stream>>>(W_r, WrsT);
    transpose_perm<<<dim3(K_ / 32, NRS / 32), 256, 0, stream>>>(W_s, WrsT + (size_t)NRS * K_);
    transpose_plain<<<dim3(K_ / 32, U_ / 32), 256, 0, stream>>>(W_q, WqT, U_);
    bias_perm<<<NC / 256, 256, 0, stream>>>(b_r, b_s, biasP);

    for (int t = 0; t < T_; t++) {
        const bf16_t* xt = xall + (size_t)t * B_ * F_;
        const bf16_t* hp = hall + (size_t)t * B_ * U_;        // h(t-1)
        bf16_t*       hn = hall + (size_t)(t + 1) * B_ * U_;  // h(t)
        gemm_rs_8ph<<<dim3(16, 32), 512, 0, stream>>>(xt, hp, WrsT, biasP, hhat, rh, sbuf);
        gemm_q_up<<<dim3(64, 8), 256, 0, stream>>>(xt, rh, WqT, b_q, sbuf, hhat, hn);
    }
    out_all<<<B_ * T_ / 4, 256, 0, stream>>>(hall + (size_t)B_ * U_, W_o, b_o, out);
}

// Round 2
// 1726.684 us; speedup vs baseline: 1.0126x; 1.0126x over previous
//
#include <hip/hip_runtime.h>
#include <hip/hip_bf16.h>
#include <math.h>

#define B_   4096
#define T_   16
#define F_   256
#define U_   512
#define M_   8
#define K_   768    // F+U
#define NRS  4096   // U*M
#define NC   8192   // combined R|S output cols
#define LNT  1.1512925f  // 0.5*ln(10)

typedef __bf16 bf16_t;
typedef bf16_t bf16x8 __attribute__((ext_vector_type(8)));
typedef bf16_t bf16x4 __attribute__((ext_vector_type(4)));
typedef float  f32x4  __attribute__((ext_vector_type(4)));

__device__ inline void gl_lds16(const void* g, void* lds) {
    __builtin_amdgcn_global_load_lds(
        (const __attribute__((address_space(1))) unsigned int*)g,
        (__attribute__((address_space(3))) unsigned int*)lds, 16, 0, 0);
}

#define VMCNT(n) asm volatile("s_waitcnt vmcnt(" #n ")" ::: "memory")
#define LGKM0()  asm volatile("s_waitcnt lgkmcnt(0)" ::: "memory")
#define BAR()    __builtin_amdgcn_s_barrier()

// ---------------------------------------------------------------------------
// Stage one 256x32 bf16 slot (16KB): 512 thr x 2 x 16B. LDS dest LINEAR
// (global_load_lds requirement); T2 swizzle applied by inverse-permuting the
// per-lane GLOBAL source column; ds_read applies the same XOR (both-sides).
// ---------------------------------------------------------------------------
__device__ inline void stageA(bf16_t* dst, const bf16_t* xt, const bf16_t* hp,
                              int m0, int k0, int tid) {
    const int r = tid >> 2;
    const int c = ((tid & 3) ^ ((tid >> 3) & 3)) * 8;
    const bf16_t *s0, *s1;
    if (k0 < F_) {
        s0 = xt + (size_t)(m0 + r) * F_ + k0 + c;
        s1 = xt + (size_t)(m0 + r + 128) * F_ + k0 + c;
    } else {
        s0 = hp + (size_t)(m0 + r) * U_ + (k0 - F_) + c;
        s1 = hp + (size_t)(m0 + r + 128) * U_ + (k0 - F_) + c;
    }
    gl_lds16(s0, (char*)dst + tid * 16);
    gl_lds16(s1, (char*)dst + (tid + 512) * 16);
}

__device__ inline void stageB(bf16_t* dst, const bf16_t* Bt, int n0, int k0, int tid) {
    const int r = tid >> 2;
    const int c = ((tid & 3) ^ ((tid >> 3) & 3)) * 8;
    gl_lds16(Bt + (size_t)(n0 + r) * K_ + k0 + c,       (char*)dst + tid * 16);
    gl_lds16(Bt + (size_t)(n0 + r + 128) * K_ + k0 + c, (char*)dst + (tid + 512) * 16);
}

__device__ inline void ds_read4(const bf16_t* base, bf16x8 (&v)[4]) {
    v[0] = *(const bf16x8*)(base);
    v[1] = *(const bf16x8*)(base + 512);
    v[2] = *(const bf16x8*)(base + 1024);
    v[3] = *(const bf16x8*)(base + 1536);
}

template <int H>
__device__ inline void mfma16(f32x4 (&acc)[8][4], const bf16x8 (&a)[4],
                              const bf16x8 (&b)[4]) {
    __builtin_amdgcn_s_setprio(1);
#pragma unroll
    for (int i = 0; i < 4; ++i)
#pragma unroll
        for (int j = 0; j < 4; ++j)
            acc[H * 4 + i][j] = __builtin_amdgcn_mfma_f32_16x16x32_bf16(
                a[i], b[j], acc[H * 4 + i][j], 0, 0, 0);
    __builtin_amdgcn_s_setprio(0);
}

// ---------------------------------------------------------------------------
// Combined R|S GEMM, 256x256 tile, 8 waves (2Mx4N), per-wave 128x64.
// LDS: per matrix 4 slots of 256x32 (K-half lo/hi x parity dbuf) = 128 KiB.
// BARRIER-MINIMAL schedule (4 barriers/K-tile, was 8): ph1/ph3 use only the
// wave-local lgkmcnt(0) before their MFMA cluster, so one wave's MFMA
// overlaps another wave's LDS-read drain (cross-wave slip). Kept barriers:
//   ph2-mid : publishes VM2 slot completion (A-hi,B-hi) for ph3's reads
//   ph2-end : all waves' A-lo reads drained before ph3 restages A-lo(t+2)
//   ph4-mid : publishes VM4 completion (A-lo,B-lo t+1) for next ph1
//   ph4-end : all waves' A-hi reads drained before ph1(t+1) restages A-hi
// Hazard trace (slip bounded by kept barriers):
//   ph1 stage A-hi(t+1): last readers ph3/ph4(t-1) drained at ph4(t-1)-end.
//   ph2 stage B-hi(t+1): last reader ph3(t-1), drained >= ph4(t-1)-mid.
//   ph3 stage A-lo(t+2): last reader ph2(t) drained at ph2(t)-end.
//   ph4 stage B-lo(t+2): last reader ph1(t); every wave's ph1-LGKM0 precedes
//                        its ph2-end arrival -> drained at ph2(t)-end.
// vmcnt(8) completes exactly the 4 oldest loads = the 2 slots needed 1 phase
// later (12 in flight peak, 4 drained per vmcnt).
// ---------------------------------------------------------------------------
__global__ __launch_bounds__(512, 2) void gemm_rs_8ph(
    const bf16_t* __restrict__ xt,     // [B_][F_]
    const bf16_t* __restrict__ hprev,  // [B_][U_]
    const bf16_t* __restrict__ Bt,     // WrsT [NC][K_] (perm)
    const float*  __restrict__ biasP,  // [NC] (perm)
    const bf16_t* __restrict__ hhat,   // [B_][NRS]
    bf16_t* __restrict__ rh,           // [B_][U_]
    bf16_t* __restrict__ sbuf)         // [B_][NRS]
{
    __shared__ bf16_t Asl[2][2][256 * 32];   // [khalf][parity] 64 KiB
    __shared__ bf16_t Bsl[2][2][256 * 32];   // 64 KiB

    const int tid  = threadIdx.x;
    const int lane = tid & 63;
    const int wave = tid >> 6;

    // Bijective XCD swizzle: XCD c owns a 4m x 16n rectangle (A-group 1.6MB
    // and B-group 6.3MB partitioned per XCD; m-fastest within keeps the
    // 4-panel A group L2-resident while B panels stream once each).
    const int lin = blockIdx.y * 16 + blockIdx.x;
    const int xcd = lin & 7, q = lin >> 3;
    const int m0 = ((xcd >> 1) * 4 + (q & 3)) * 256;
    const int n0 = ((xcd & 1) * 16 + (q >> 2)) * 256;

    const int wm = wave >> 2;          // 0..1
    const int wn = wave & 3;           // 0..3
    const int lr = lane & 15;
    const int kq = lane >> 4;
    // T2 read-side swizzle: 16B-slot = kq ^ ((row>>1)&3); row=16a+lr -> lane-uniform.
    const int cr = (kq ^ ((lr >> 1) & 3)) * 8;

    const int aoff0 = (wm * 128 + lr) * 32 + cr;        // M-half 0
    const int aoff1 = (wm * 128 + 64 + lr) * 32 + cr;   // M-half 1
    const int boff  = (wn * 64 + lr) * 32 + cr;

    f32x4 acc[8][4] = {};
    bf16x8 a[4], b[4];

    // Prologue: 6 slots (12 loads) in flight; vmcnt(8) -> A-lo0,B-lo0 landed.
    stageA(&Asl[0][0][0], xt, hprev, m0, 0,  tid);
    stageB(&Bsl[0][0][0], Bt, n0, 0,  tid);
    stageA(&Asl[1][0][0], xt, hprev, m0, 32, tid);
    stageB(&Bsl[1][0][0], Bt, n0, 32, tid);
    stageA(&Asl[0][1][0], xt, hprev, m0, 64, tid);
    stageB(&Bsl[0][1][0], Bt, n0, 64, tid);
    VMCNT(8);
    BAR();

#define TILE(T, VM2, VM4, S12, S34)                                           \
  {                                                                           \
    const int p_ = (T) & 1, pn_ = p_ ^ 1;                                     \
    /* ph1 (no barrier: wave-local decouple) */                               \
    ds_read4(&Asl[0][p_][0] + aoff0, a);                                      \
    ds_read4(&Bsl[0][p_][0] + boff, b);                                       \
    if (S12) stageA(&Asl[1][pn_][0], xt, hprev, m0, ((T) + 1) * 64 + 32, tid);\
    LGKM0();                                                                  \
    mfma16<0>(acc, a, b);                                                     \
    /* ph2 */                                                                 \
    ds_read4(&Asl[0][p_][0] + aoff1, a);                                      \
    if (S12) stageB(&Bsl[1][pn_][0], Bt, n0, ((T) + 1) * 64 + 32, tid);       \
    VMCNT(VM2); BAR(); LGKM0();                                               \
    mfma16<1>(acc, a, b);                                                     \
    BAR();                                                                    \
    /* ph3 (no barrier) */                                                    \
    ds_read4(&Asl[1][p_][0] + aoff0, a);                                      \
    ds_read4(&Bsl[1][p_][0] + boff, b);                                       \
    if (S34) stageA(&Asl[0][p_][0], xt, hprev, m0, ((T) + 2) * 64, tid);      \
    LGKM0();                                                                  \
    mfma16<0>(acc, a, b);                                                     \
    /* ph4 */                                                                 \
    ds_read4(&Asl[1][p_][0] + aoff1, a);                                      \
    if (S34) stageB(&Bsl[0][p_][0], Bt, n0, ((T) + 2) * 64, tid);             \
    VMCNT(VM4); BAR(); LGKM0();                                               \
    mfma16<1>(acc, a, b);                                                     \
    BAR();                                                                    \
  }

    for (int tt = 0; tt < 10; ++tt) TILE(tt, 8, 8, 1, 1);
    TILE(10, 8, 4, 1, 0);
    TILE(11, 0, 0, 0, 0);
#undef TILE

    // ------------------- fused softmax epilogue (unchanged math) -----------
    const int nb  = n0 + wn * 64;
    const int u3  = lane & 7;
    const int m0v = ((lane >> 3) & 1) * 4;
    const bool is_r = nb < NRS;

    float bj[4];
#pragma unroll
    for (int j = 0; j < 4; ++j) bj[j] = biasP[nb + j * 16 + lr];

#pragma unroll
    for (int mi = 0; mi < 8; ++mi) {
        const int rowb = m0 + wm * 128 + mi * 16 + kq * 4;
#pragma unroll
        for (int r = 0; r < 4; ++r) {
            const int row = rowb + r;
            float e[4], sum = 0.f;
#pragma unroll
            for (int j = 0; j < 4; ++j) {
                float v = acc[mi][j][r] + bj[j];
                float d = v - (float)(m0v + j) * LNT;
                e[j] = __expf(-d * d);
                sum += e[j];
            }
            sum += __shfl_xor(sum, 8, 64);
            const float inv = 1.0f / sum;
            if (is_r) {
                bf16x4 h4 = *(const bf16x4*)(hhat + (size_t)row * NRS + nb + u3 * 8 + m0v);
                float rhv = 0.f;
#pragma unroll
                for (int j = 0; j < 4; ++j) rhv += e[j] * inv * (float)h4[j];
                rhv += __shfl_xor(rhv, 8, 64);
                if ((lane & 8) == 0)
                    rh[(size_t)row * U_ + (nb >> 3) + u3] = (bf16_t)rhv;
            } else {
                bf16x4 pv;
#pragma unroll
                for (int j = 0; j < 4; ++j) pv[j] = (bf16_t)(e[j] * inv);
                *(bf16x4*)(sbuf + (size_t)row * NRS + (nb - NRS) + u3 * 8 + m0v) = pv;
            }
        }
    }
}

// ---------------------------------------------------------------------------
// q GEMM (64x64 tiles, grid 64x8=512) + fused state update; writes this
// step's hidden into hall slice t (persistent; next rs reads it as hprev).
// ---------------------------------------------------------------------------
__global__ __launch_bounds__(256) void gemm_q_up(
    const bf16_t* __restrict__ xt,     // [B_][F_]
    const bf16_t* __restrict__ rh,     // [B_][U_]
    const bf16_t* __restrict__ Bq,     // WqT [U_][K_]
    const float*  __restrict__ bq,
    const bf16_t* __restrict__ sbuf,
    bf16_t* __restrict__ hhat,
    bf16_t* __restrict__ hnext)        // hall slice t: [B_][U_]
{
    __shared__ bf16_t Al[2][64 * 32];
    __shared__ bf16_t Bl[2][64 * 32];

    const int tid  = threadIdx.x;
    const int lane = tid & 63;
    const int wave = tid >> 6;
    const int m0 = blockIdx.x * 64;
    const int n0 = blockIdx.y * 64;
    const int wm = (wave & 1) * 32;
    const int wn = (wave >> 1) * 32;
    const int lr = lane & 15;
    const int kq = lane >> 4;

    f32x4 acc[2][2] = {};

    const int rA = tid >> 2;
    const int kc = (tid & 3) * 8;

    for (int kk = 0; kk < K_; kk += 64) {
        const bf16_t* arow;
        int cbase;
        if (kk < F_) { arow = xt + (size_t)(m0 + rA) * F_; cbase = kk; }
        else         { arow = rh + (size_t)(m0 + rA) * U_; cbase = kk - F_; }

        __syncthreads();
        gl_lds16(arow + cbase + kc,      (char*)&Al[0][0] + tid * 16);
        gl_lds16(arow + cbase + 32 + kc, (char*)&Al[1][0] + tid * 16);
        gl_lds16(Bq + (size_t)(n0 + rA) * K_ + kk + kc,      (char*)&Bl[0][0] + tid * 16);
        gl_lds16(Bq + (size_t)(n0 + rA) * K_ + kk + 32 + kc, (char*)&Bl[1][0] + tid * 16);
        __syncthreads();

#pragma unroll
        for (int s = 0; s < 2; s++) {
            bf16x8 af[2], bfr[2];
#pragma unroll
            for (int i = 0; i < 2; i++)
                af[i] = *(const bf16x8*)(&Al[s][0] + (wm + i * 16 + lr) * 32 + kq * 8);
#pragma unroll
            for (int i = 0; i < 2; i++)
                bfr[i] = *(const bf16x8*)(&Bl[s][0] + (wn + i * 16 + lr) * 32 + kq * 8);
#pragma unroll
            for (int i = 0; i < 2; i++)
#pragma unroll
                for (int j = 0; j < 2; j++)
                    acc[i][j] = __builtin_amdgcn_mfma_f32_16x16x32_bf16(
                        af[i], bfr[j], acc[i][j], 0, 0, 0);
        }
    }

    const float DEC[8] = {0.0f, 0.9658531f, 0.9827783f, 0.9884856f,
                          0.9913518f, 0.9930754f, 0.9942261f, 0.9950489f};

#pragma unroll
    for (int i = 0; i < 2; i++) {
        const int rowb = m0 + wm + i * 16 + kq * 4;
#pragma unroll
        for (int j = 0; j < 2; j++) {
            const int u = n0 + wn + j * 16 + lr;
            const float bv = bq[u];
#pragma unroll
            for (int r = 0; r < 4; r++) {
                const int row = rowb + r;
                const float q = tanhf(acc[i][j][r] + bv);
                const size_t base = (size_t)row * NRS + u * 8;
                bf16x8 s8 = *(const bf16x8*)(sbuf + base);
                bf16x8 h8 = *(const bf16x8*)(hhat + base);
                bf16x8 ho;
                float hs = 0.f;
#pragma unroll
                for (int m = 0; m < 8; m++) {
                    float s = (float)s8[m];
                    float h = (float)h8[m];
                    float hn = ((1.f - s) * h + s * q) * DEC[m];
                    ho[m] = (bf16_t)hn;
                    hs += hn;
                }
                *(bf16x8*)(hhat + base) = ho;
                hnext[(size_t)row * U_ + u] = (bf16_t)hs;
            }
        }
    }
}

// dst[p][K_] = bf16(src[K_][NRS] col L), rows permuted within 64-groups.
__global__ void transpose_perm(const float* __restrict__ src, bf16_t* __restrict__ dst) {
    __shared__ float tl[32][33];
    int k0 = blockIdx.x * 32, n0 = blockIdx.y * 32;
    int tx = threadIdx.x & 31, ty = threadIdx.x >> 5;
#pragma unroll
    for (int i = 0; i < 32; i += 8)
        tl[ty + i][tx] = src[(size_t)(k0 + ty + i) * NRS + n0 + tx];
    __syncthreads();
#pragma unroll
    for (int i = 0; i < 32; i += 8) {
        int n = n0 + ty + i;
        int m = n & 7, u3v = (n >> 3) & 7;
        int p = (n & ~63) + (m & 3) * 16 + (m >> 2) * 8 + u3v;
        dst[(size_t)p * K_ + k0 + tx] = (bf16_t)tl[tx][ty + i];
    }
}

// plain transpose: dst[N][K_] = bf16(src[K_][N]^T)
__global__ void transpose_plain(const float* __restrict__ src, bf16_t* __restrict__ dst, int N) {
    __shared__ float tl[32][33];
    int k0 = blockIdx.x * 32, n0 = blockIdx.y * 32;
    int tx = threadIdx.x & 31, ty = threadIdx.x >> 5;
#pragma unroll
    for (int i = 0; i < 32; i += 8)
        tl[ty + i][tx] = src[(size_t)(k0 + ty + i) * N + n0 + tx];
    __syncthreads();
#pragma unroll
    for (int i = 0; i < 32; i += 8)
        dst[(size_t)(n0 + ty + i) * K_ + k0 + tx] = (bf16_t)tl[tx][ty + i];
}

__global__ void bias_perm(const float* __restrict__ b_r, const float* __restrict__ b_s,
                          float* __restrict__ biasP) {
    int p = blockIdx.x * 256 + threadIdx.x;  // NC
    int pr = p & 63, j = pr >> 4, lr = pr & 15;
    int L = (p & ~63) + (lr & 7) * 8 + ((lr >> 3) & 1) * 4 + j;
    biasP[p] = (L < NRS) ? b_r[L] : b_s[L - NRS];
}

// xall[t][b][f] = bf16(x[b][t][f])
__global__ void xall_build(const float* __restrict__ x, bf16_t* __restrict__ xall) {
    int idx = blockIdx.x * 256 + threadIdx.x;  // B_*T_*F_
    int b = idx >> 12;
    int rem = idx & 4095;
    int t = rem >> 8, f = rem & 255;
    xall[((size_t)t * B_ + b) * F_ + f] = (bf16_t)x[idx];
}

// One launch for all T steps: out[b,t,:] = hall[t][b][:] @ Wout + bout.
__global__ __launch_bounds__(256) void out_all(
    const bf16_t* __restrict__ hall,   // [T_][B_][U_] (slices 1..16 of alloc)
    const float* __restrict__ Wout,
    const float* __restrict__ bout,
    float* __restrict__ out)
{
    int row = blockIdx.x * 4 + (threadIdx.x >> 6);  // t*B_ + b
    int lane = threadIdx.x & 63;
    bf16x8 h8 = *(const bf16x8*)(hall + (size_t)row * U_ + lane * 8);
    float p0 = 0, p1 = 0, p2 = 0;
#pragma unroll
    for (int k = 0; k < 8; k++) {
        float h = (float)h8[k];
        int u = lane * 8 + k;
        p0 += h * Wout[u * 3 + 0];
        p1 += h * Wout[u * 3 + 1];
        p2 += h * Wout[u * 3 + 2];
    }
    for (int off = 32; off; off >>= 1) {
        p0 += __shfl_down(p0, off, 64);
        p1 += __shfl_down(p1, off, 64);
        p2 += __shfl_down(p2, off, 64);
    }
    if (lane == 0) {
        int t = row >> 12, b = row & (B_ - 1);
        size_t o = ((size_t)b * T_ + t) * 3;
        out[o + 0] = p0 + bout[0];
        out[o + 1] = p1 + bout[1];
        out[o + 2] = p2 + bout[2];
    }
}

extern "C" void kernel_launch(void* const* d_in, const int* in_sizes, int n_in,
                              void* d_out, int out_size, void* d_ws, size_t ws_size,
                              hipStream_t stream) {
    const float* x   = (const float*)d_in[0];
    const float* W_r = (const float*)d_in[1];
    const float* b_r = (const float*)d_in[2];
    const float* W_q = (const float*)d_in[3];
    const float* b_q = (const float*)d_in[4];
    const float* W_s = (const float*)d_in[5];
    const float* b_s = (const float*)d_in[6];
    const float* W_o = (const float*)d_in[7];
    const float* b_o = (const float*)d_in[8];
    float* out = (float*)d_out;

    char* ws = (char*)d_ws;
    bf16_t* hhat  = (bf16_t*)ws; ws += (size_t)B_ * NRS * 2;         // 32 MB
    bf16_t* sbuf  = (bf16_t*)ws; ws += (size_t)B_ * NRS * 2;         // 32 MB
    bf16_t* xall  = (bf16_t*)ws; ws += (size_t)B_ * T_ * F_ * 2;     // 32 MB
    bf16_t* hall  = (bf16_t*)ws; ws += (size_t)(T_ + 1) * B_ * U_ * 2; // 68 MB
    bf16_t* rh    = (bf16_t*)ws; ws += (size_t)B_ * U_ * 2;          // 4 MB
    bf16_t* WrsT  = (bf16_t*)ws; ws += (size_t)NC * K_ * 2;          // 12 MB
    bf16_t* WqT   = (bf16_t*)ws; ws += (size_t)U_ * K_ * 2;          // 0.75 MB
    float*  biasP = (float*)ws;  ws += (size_t)NC * 4;               // 32 KB

    hipMemsetAsync(hhat, 0, (size_t)B_ * NRS * 2, stream);
    hipMemsetAsync(hall, 0, (size_t)B_ * U_ * 2, stream);  // slice 0 = h(-1)=0
    xall_build<<<B_ * T_ * F_ / 256, 256, 0, stream>>>(x, xall);
    transpose_perm<<<dim3(K_ / 32, NRS / 32), 256, 0, stream>>>(W_r, WrsT);
    transpose_perm<<<dim3(K_ / 32, NRS / 32), 256, 0, stream>>>(W_s, WrsT + (size_t)NRS * K_);
    transpose_plain<<<dim3(K_ / 32, U_ / 32), 256, 0, stream>>>(W_q, WqT, U_);
    bias_perm<<<NC / 256, 256, 0, stream>>>(b_r, b_s, biasP);

    for (int t = 0; t < T_; t++) {
        const bf16_t* xt = xall + (size_t)t * B_ * F_;
        const bf16_t* hp = hall + (size_t)t * B_ * U_;        // h(t-1)
        bf16_t*       hn = hall + (size_t)(t + 1) * B_ * U_;  // h(t)
        gemm_rs_8ph<<<dim3(16, 32), 512, 0, stream>>>(xt, hp, WrsT, biasP, hhat, rh, sbuf);
        gemm_q_up<<<dim3(64, 8), 256, 0, stream>>>(xt, rh, WqT, b_q, sbuf, hhat, hn);
    }
    out_all<<<B_ * T_ / 4, 256, 0, stream>>>(hall + (size_t)B_ * U_, W_o, b_o, out);
}